// Round 1
// baseline (240.710 us; speedup 1.0000x reference)
//
#include <hip/hip_runtime.h>

// BioConvolution: 256 independent per-location GEMMs
//   C_l (64 x 128) = A_l (64 x 1024) * B_l (1024 x 128) + bias, ReLU
// A_l[n][k] = X[n, r*4+i, c*4+j, ch]   (k = i*256 + j*64 + ch), l = r*16+c
// B_l[k][f] = filters[l*131072 + k*128 + f]
// out[n, l, f] = n*32768 + l*128 + f

typedef __bf16 bf16x8 __attribute__((ext_vector_type(8)));
typedef float f32x4 __attribute__((ext_vector_type(4)));

#define SA 72   // A LDS row stride (ushort units), padded: 144B rows, 16B-aligned frags
#define SB 132  // B LDS k-pair row stride (uint units): 528B rows, 16B-aligned writes

__device__ __forceinline__ unsigned short f2bf(float f) {
  unsigned u = __builtin_bit_cast(unsigned, f);
  u += 0x7fffu + ((u >> 16) & 1u);  // round-to-nearest-even
  return (unsigned short)(u >> 16);
}
__device__ __forceinline__ unsigned pack2(float a, float b) {
  return (unsigned)f2bf(a) | ((unsigned)f2bf(b) << 16);
}

__global__ __launch_bounds__(256) void bioconv_mfma(
    const float* __restrict__ X, const float* __restrict__ Fw,
    const float* __restrict__ bias, float* __restrict__ out) {
  const int l = blockIdx.x;
  const int r = l >> 4;
  const int c = l & 15;
  const int t = threadIdx.x;
  const int w = t >> 6;        // wave 0..3 -> f columns [w*32, w*32+32)
  const int lane = t & 63;
  const int q = lane >> 4;     // quad 0..3
  const int nl = lane & 15;

  __shared__ __align__(16) unsigned short As[2][64 * SA];  // 2 x 9216 B
  __shared__ __align__(16) unsigned Bs[2][32 * SB];        // 2 x 16896 B (k-pairs packed)

  const float* Fl = Fw + (size_t)l * 131072;

  f32x4 acc[4][2];
#pragma unroll
  for (int mb = 0; mb < 4; ++mb)
#pragma unroll
    for (int fb = 0; fb < 2; ++fb)
      acc[mb][fb] = (f32x4){0.f, 0.f, 0.f, 0.f};

  float4 areg[4], b0reg[4], b1reg[4];

  // staging index split (thread-constant)
  const int a_n0 = t >> 4;        // A: 16 threads cover one 256B row segment
  const int a_f4 = t & 15;
  const int b_kp0 = t >> 5;       // B: 32 threads cover one 512B k-row
  const int b_f = (t & 31) << 2;

  const float* xrowbase = X + c * 256 + a_f4 * 4;

  auto issue_loads = [&](int s) {
    const int i = s >> 2;
    const int koff = (s & 3) << 6;
    const float* xb = xrowbase + (r * 4 + i) * 4096 + koff;
#pragma unroll
    for (int rep = 0; rep < 4; ++rep) {
      const int n = a_n0 + (rep << 4);
      areg[rep] = *(const float4*)(xb + (size_t)n * 262144);
    }
    const float* fbse = Fl + s * 8192 + b_f;
#pragma unroll
    for (int rep = 0; rep < 4; ++rep) {
      const int kp = b_kp0 + (rep << 3);
      const float* g = fbse + kp * 256;
      b0reg[rep] = *(const float4*)(g);         // k even row
      b1reg[rep] = *(const float4*)(g + 128);   // k odd row
    }
  };

  auto store_lds = [&](int buf) {
#pragma unroll
    for (int rep = 0; rep < 4; ++rep) {
      const int n = a_n0 + (rep << 4);
      uint2 v;
      v.x = pack2(areg[rep].x, areg[rep].y);
      v.y = pack2(areg[rep].z, areg[rep].w);
      *(uint2*)&As[buf][n * SA + a_f4 * 4] = v;
    }
#pragma unroll
    for (int rep = 0; rep < 4; ++rep) {
      const int kp = b_kp0 + (rep << 3);
      uint4 v;  // word j = (bf16 B[2kp][f+j]) | (bf16 B[2kp+1][f+j] << 16)
      v.x = pack2(b0reg[rep].x, b1reg[rep].x);
      v.y = pack2(b0reg[rep].y, b1reg[rep].y);
      v.z = pack2(b0reg[rep].z, b1reg[rep].z);
      v.w = pack2(b0reg[rep].w, b1reg[rep].w);
      *(uint4*)&Bs[buf][kp * SB + b_f] = v;
    }
  };

  issue_loads(0);
  store_lds(0);

  for (int s = 0; s < 16; ++s) {
    __syncthreads();                 // buf[s&1] writes visible; prev readers done
    if (s < 15) issue_loads(s + 1);  // overlap with compute below
    const int buf = s & 1;
#pragma unroll
    for (int kc = 0; kc < 2; ++kc) {
      bf16x8 af[4];
#pragma unroll
      for (int mb = 0; mb < 4; ++mb)
        af[mb] = *(const bf16x8*)&As[buf][(mb * 16 + nl) * SA + kc * 32 + q * 8];
      bf16x8 bfr[2];
#pragma unroll
      for (int fb = 0; fb < 2; ++fb) {
        const unsigned* bp = &Bs[buf][(kc * 16 + q * 4) * SB + (w * 32 + fb * 16 + nl)];
        uint4 v;
        v.x = bp[0];
        v.y = bp[SB];
        v.z = bp[2 * SB];
        v.w = bp[3 * SB];
        bfr[fb] = __builtin_bit_cast(bf16x8, v);
      }
#pragma unroll
      for (int mb = 0; mb < 4; ++mb)
#pragma unroll
        for (int fb = 0; fb < 2; ++fb)
          acc[mb][fb] = __builtin_amdgcn_mfma_f32_16x16x32_bf16(
              af[mb], bfr[fb], acc[mb][fb], 0, 0, 0);
    }
    if (s < 15) store_lds((s + 1) & 1);  // other buffer; safe w/ one barrier/iter
  }

  // epilogue: bias + ReLU, D layout: row = q*4 + reg, col = nl
#pragma unroll
  for (int fb = 0; fb < 2; ++fb) {
    const int f = w * 32 + fb * 16 + nl;
    const float bv = bias[f];
    float* ob = out + (size_t)l * 128 + f;
#pragma unroll
    for (int mb = 0; mb < 4; ++mb) {
#pragma unroll
      for (int v = 0; v < 4; ++v) {
        const int row = mb * 16 + q * 4 + v;
        const float val = acc[mb][fb][v] + bv;
        ob[(size_t)row * 32768] = fmaxf(val, 0.f);
      }
    }
  }
}

extern "C" void kernel_launch(void* const* d_in, const int* in_sizes, int n_in,
                              void* d_out, int out_size, void* d_ws, size_t ws_size,
                              hipStream_t stream) {
  const float* X = (const float*)d_in[0];
  const float* Fw = (const float*)d_in[1];
  const float* bias = (const float*)d_in[2];
  float* out = (float*)d_out;
  bioconv_mfma<<<256, 256, 0, stream>>>(X, Fw, bias, out);
}